// Round 8
// baseline (329.403 us; speedup 1.0000x reference)
//
#include <hip/hip_runtime.h>

typedef __attribute__((ext_vector_type(8))) short bf16x8;
typedef __attribute__((ext_vector_type(4))) float f32x4;
typedef __attribute__((ext_vector_type(2))) unsigned int u32x2;

constexpr int D = 64;
constexpr int SEG = 64;    // relation-segment padding granule = edges per wave
constexpr int CSTR = 16;   // counter stride (ints): 1 atomic counter per 64B line
constexpr int SBS = 1024;  // scatter/count block size (edges per block)

__device__ inline unsigned short f2bf(float f) {  // RNE fp32->bf16
  unsigned u = __float_as_uint(f);
  u += 0x7fff + ((u >> 16) & 1);
  return (unsigned short)(u >> 16);
}
__device__ inline float bflo(unsigned u) { return __uint_as_float(u << 16); }
__device__ inline float bfhi(unsigned u) { return __uint_as_float(u & 0xffff0000u); }

// ---- counting (blocks < nbE) + fused convert (blocks >= nbE) ----
// count: per-block relation histogram -> bcnt[r*nbE+b]; padded deg atomics.
// cvt:   xb vectorized 8/thread; W transpose via [64][65] LDS tile.
__global__ __launch_bounds__(SBS) void count_cvt_kernel(
    const int* __restrict__ dst, const int* __restrict__ et,
    int* __restrict__ bcnt, int* __restrict__ deg, int E, int R, int nbE,
    const float* __restrict__ x, unsigned short* __restrict__ xb, int nx, int nxb,
    const float* __restrict__ W1, unsigned short* __restrict__ WT1,
    const float* __restrict__ W2, unsigned short* __restrict__ WT2,
    const float* __restrict__ Wl1, unsigned short* __restrict__ WTl1,
    const float* __restrict__ Wl2, unsigned short* __restrict__ WTl2) {
  int b = blockIdx.x;
  int t = threadIdx.x;
  if (b < nbE) {
    __shared__ int lh[128];
    if (t < 128) lh[t] = 0;
    __syncthreads();
    int e = b * SBS + t;
    if (e < E) {
      atomicAdd(&deg[(long)dst[e] * CSTR], 1);   // one counter per cache line
      atomicAdd(&lh[et[e]], 1);
    }
    __syncthreads();
    if (t < R) bcnt[t * nbE + b] = lh[t];
    return;
  }
  b -= nbE;
  if (b < nxb) {
    long i = ((long)b * SBS + t) * 8;
    if (i < nx) {                            // nx % 8 == 0 (N*D, D=64)
      float4 f0 = *(const float4*)(x + i);
      float4 f1 = *(const float4*)(x + i + 4);
      bf16x8 o;
      o[0] = (short)f2bf(f0.x); o[1] = (short)f2bf(f0.y);
      o[2] = (short)f2bf(f0.z); o[3] = (short)f2bf(f0.w);
      o[4] = (short)f2bf(f1.x); o[5] = (short)f2bf(f1.y);
      o[6] = (short)f2bf(f1.z); o[7] = (short)f2bf(f1.w);
      *(bf16x8*)(xb + i) = o;
    }
    return;
  }
  const int m = b - nxb;                     // matrix index in [0, 2R+2)
  const float* Wsrc;
  unsigned short* Wdst;
  if (m < R)          { Wsrc = W1 + ((long)m << 12);        Wdst = WT1 + ((long)m << 12); }
  else if (m < 2 * R) { Wsrc = W2 + ((long)(m - R) << 12);  Wdst = WT2 + ((long)(m - R) << 12); }
  else if (m == 2 * R){ Wsrc = Wl1;                         Wdst = WTl1; }
  else                { Wsrc = Wl2;                         Wdst = WTl2; }
  __shared__ float tile[64][65];
#pragma unroll
  for (int it = 0; it < 4; ++it) {
    int idx = it * SBS + t;                  // k = idx>>6 (row), n = idx&63 (col)
    tile[idx >> 6][idx & 63] = Wsrc[idx];
  }
  __syncthreads();
#pragma unroll
  for (int it = 0; it < 4; ++it) {
    int j = it * SBS + t;                    // out index: n = j>>6, k = j&63
    Wdst[j] = f2bf(tile[j & 63][j >> 6]);    // coalesced bf16 store
  }
}

// ---- dual-region 3-phase exclusive scan: bcnt (dense) + deg (strided) ----
__global__ __launch_bounds__(256) void scanA_dual_kernel(
    const int* __restrict__ bcnt, const int* __restrict__ deg,
    int* __restrict__ bsum, int nBC, int N, int nbBC) {
  __shared__ int s[256];
  int t = threadIdx.x;
  int b = blockIdx.x;
  int v;
  if (b < nbBC) {
    int i = b * 256 + t;
    v = (i < nBC) ? bcnt[i] : 0;
  } else {
    int i = (b - nbBC) * 256 + t;
    v = (i < N) ? deg[(long)i * CSTR] : 0;
  }
  s[t] = v;
  __syncthreads();
  for (int o = 128; o > 0; o >>= 1) {
    if (t < o) s[t] += s[t + o];
    __syncthreads();
  }
  if (t == 0) bsum[b] = s[0];
}

__device__ inline void scanB_region(int* bsum, int nb, int t) {
  __shared__ int s[256];
  __shared__ int carry;
  if (t == 0) carry = 0;
  __syncthreads();
  for (int base = 0; base < nb; base += 256) {
    int i = base + t;
    int v = (i < nb) ? bsum[i] : 0;
    s[t] = v;
    __syncthreads();
    for (int o = 1; o < 256; o <<= 1) {
      int u = (t >= o) ? s[t - o] : 0;
      __syncthreads();
      s[t] += u;
      __syncthreads();
    }
    if (i < nb) bsum[i] = carry + s[t] - v;   // exclusive
    __syncthreads();
    if (t == 0) carry += s[255];
    __syncthreads();
  }
}

__global__ __launch_bounds__(256) void scanB_dual_kernel(
    int* __restrict__ bsum, int nbBC, int nbN) {
  int t = threadIdx.x;
  scanB_region(bsum, nbBC, t);
  scanB_region(bsum + nbBC, nbN, t);
}

// blocks < nbBC: bcnt -> prefE (+ total); blocks >= nbBC: deg -> dstoff/cur2
__global__ __launch_bounds__(256) void scanC_dual_kernel(
    const int* __restrict__ bcnt, const int* __restrict__ deg,
    const int* __restrict__ bsum, int* __restrict__ prefE,
    int* __restrict__ dstoff, int* __restrict__ cur2,
    int nBC, int N, int nbBC) {
  __shared__ int s[256];
  int t = threadIdx.x;
  int b = blockIdx.x;
  bool isBC = (b < nbBC);
  int i = (isBC ? b : b - nbBC) * 256 + t;
  int n = isBC ? nBC : N;
  int v = 0;
  if (i < n) v = isBC ? bcnt[i] : deg[(long)i * CSTR];
  s[t] = v;
  __syncthreads();
  for (int o = 1; o < 256; o <<= 1) {
    int u = (t >= o) ? s[t - o] : 0;
    __syncthreads();
    s[t] += u;
    __syncthreads();
  }
  int excl = bsum[b] + s[t] - v;
  if (isBC) {
    if (i < n) prefE[i] = excl;
    if (i == n - 1) prefE[n] = excl + v;
  } else {
    if (i < n) { dstoff[i] = excl; cur2[(long)i * CSTR] = excl; }
    if (i == n - 1) dstoff[n] = excl + v;
  }
}

// ---- counting-sort scatter with inline padded-cursor scan + pad fills ----
// Replaces prefix_wrel: every block recomputes cursor[] (cheap 128-wide scan);
// blocks 0..R-1 fill their relation's eidx pads + wrel range; block R fills
// the global tails. Records LDS-reordered for coalesced eidx stores.
__global__ __launch_bounds__(SBS) void scatter_kernel(
    const int* __restrict__ src, const int* __restrict__ dst, const int* __restrict__ et,
    const int* __restrict__ prefE, int* __restrict__ cur2,
    int2* __restrict__ eidx, int* __restrict__ wrel,
    int E, int R, int nbE, int Ecap, int nwavesTot) {
  __shared__ int lh[128];
  __shared__ int lbase[128];
  __shared__ int lpre[128];
  __shared__ int scur[128];
  __shared__ int stot[128];
  __shared__ int sv[SBS];
  __shared__ int jv[SBS];
  __shared__ int rv[SBS];
  int t = threadIdx.x, b = blockIdx.x;
  // ---- inline padded cursor scan over relations ----
  int myc = 0, mytot = 0;
  if (t < 128) {
    if (t < R) {
      mytot = prefE[(t + 1) * nbE] - prefE[t * nbE];
      myc = (mytot + SEG - 1) & ~(SEG - 1);
    }
    lpre[t] = myc;
  }
  __syncthreads();
  for (int o = 1; o < 128; o <<= 1) {
    int u = (t >= o && t < 128) ? lpre[t - o] : 0;
    __syncthreads();
    if (t < 128) lpre[t] += u;
    __syncthreads();
  }
  if (t < 128) {
    scur[t] = lpre[t] - myc;                 // exclusive padded prefix = cursor
    stot[t] = mytot;
    lh[t] = 0;
    lbase[t] = (t < R) ? (scur[t] + prefE[t * nbE + b] - prefE[t * nbE]) : 0;
  }
  __syncthreads();
  // ---- distributed pad fills (relations grid-strided over blocks) ----
  for (int rr = b; rr <= R; rr += nbE) {
    if (rr < R) {
      int cur = scur[rr], tot = stot[rr];
      int c = (tot + SEG - 1) & ~(SEG - 1);
      for (int p = cur + tot + t; p < cur + c; p += SBS) eidx[p] = make_int2(-1, -1);
      int w0 = cur >> 6, nw2 = c >> 6;
      for (int w = t; w < nw2; w += SBS) wrel[w0 + w] = rr;
    } else {
      int total = scur[127];                 // padded grand total (c=0 for t>=R)
      for (int p = total + t; p < Ecap; p += SBS) eidx[p] = make_int2(-1, -1);
      for (int w = (total >> 6) + t; w < nwavesTot; w += SBS) wrel[w] = 0;
    }
  }
  // ---- main scatter ----
  int e = b * SBS + t;
  bool valid = (e < E);
  int r = 0, s = 0, jd = 0, lr = 0;
  if (valid) {
    r = et[e]; s = src[e]; int d = dst[e];
    lr = atomicAdd(&lh[r], 1);                    // within-block rank (LDS)
    jd = atomicAdd(&cur2[(long)d * CSTR], 1);     // own line -> pipelined RMW
  }
  __syncthreads();
  if (t < 128) lpre[t] = lh[t];
  __syncthreads();
  for (int o = 1; o < 128; o <<= 1) {             // inclusive scan of lh
    int u = (t >= o && t < 128) ? lpre[t - o] : 0;
    __syncthreads();
    if (t < 128) lpre[t] += u;
    __syncthreads();
  }
  if (valid) {
    int slot = (lpre[r] - lh[r]) + lr;            // exclusive base + rank
    sv[slot] = s; jv[slot] = jd; rv[slot] = r;
  }
  __syncthreads();
  int nvalid = min(E - b * SBS, SBS);
  if (t < nvalid) {
    int rr2 = rv[t];
    int ex = lpre[rr2] - lh[rr2];
    int pos = lbase[rr2] + (t - ex);              // consecutive t -> consecutive pos
    eidx[pos] = make_int2(sv[t], jv[t]);
  }
}

// ---- Phase A: MFMA matvec, stream raw msgs; deep-pipelined loads ----
// msg row layout (32 dwords, interleaved): dword 2k = cols (k, k+16);
// dword 2k+1 = cols (32+k, 48+k). One uint2 (8B) store per lane per edge-row.
__global__ __launch_bounds__(256)
void msg_kernel(const unsigned short* __restrict__ xb,
                const unsigned short* __restrict__ WT,
                const int2* __restrict__ eidx, const int* __restrict__ wrel,
                unsigned int* __restrict__ msgp, int* __restrict__ relrow, int nwaves) {
  const int lane = (int)threadIdx.x & 63;
  const int l15 = lane & 15;
  const int q = lane >> 4;
  // bijective XCD swizzle (T1): contiguous wave (=relation) ranges per XCD
  const int nwg = (int)gridDim.x;
  const int bid = (int)blockIdx.x;
  const int xcd = bid & 7, idx = bid >> 3;
  const int qq = nwg >> 3, rr = nwg & 7;
  const int swz = (xcd < rr ? xcd * (qq + 1) : rr * (qq + 1) + (xcd - rr) * qq) + idx;
  const int wave = swz * 4 + ((int)threadIdx.x >> 6);
  if (wave >= nwaves) return;
  const long base = (long)wave * SEG;
  const int r = wrel[wave];                 // wave-uniform relation (0 for pad tail)
  const unsigned short* wb = WT + ((long)r << 12);
  // issue ALL edge-record loads first, then B frags, then all A frags:
  // ~12 outstanding global loads per wave before the first MFMA.
  int2 rec[4];
#pragma unroll
  for (int t = 0; t < 4; ++t) rec[t] = eidx[base + t * 16 + l15];
  bf16x8 Bf[4][2];
#pragma unroll
  for (int nt = 0; nt < 4; ++nt)
#pragma unroll
    for (int kh = 0; kh < 2; ++kh)
      Bf[nt][kh] = *(const bf16x8*)(wb + (nt * 16 + l15) * 64 + kh * 32 + q * 8);
  bf16x8 A[4][2];
#pragma unroll
  for (int t = 0; t < 4; ++t) {
    const unsigned short* xr = xb + ((long)max(rec[t].x, 0) << 6);
    A[t][0] = *(const bf16x8*)(xr + q * 8);
    A[t][1] = *(const bf16x8*)(xr + 32 + q * 8);
  }
  if (relrow) {                              // graph-invariant: L1 only
#pragma unroll
    for (int t = 0; t < 4; ++t)
      if (lane < 16 && rec[t].y >= 0) relrow[rec[t].y] = r;
  }
#pragma unroll
  for (int t = 0; t < 4; ++t) {
    f32x4 acc0 = (f32x4)0.0f, acc1 = (f32x4)0.0f, acc2 = (f32x4)0.0f, acc3 = (f32x4)0.0f;
    acc0 = __builtin_amdgcn_mfma_f32_16x16x32_bf16(A[t][0], Bf[0][0], acc0, 0, 0, 0);
    acc0 = __builtin_amdgcn_mfma_f32_16x16x32_bf16(A[t][1], Bf[0][1], acc0, 0, 0, 0);
    acc1 = __builtin_amdgcn_mfma_f32_16x16x32_bf16(A[t][0], Bf[1][0], acc1, 0, 0, 0);
    acc1 = __builtin_amdgcn_mfma_f32_16x16x32_bf16(A[t][1], Bf[1][1], acc1, 0, 0, 0);
    acc2 = __builtin_amdgcn_mfma_f32_16x16x32_bf16(A[t][0], Bf[2][0], acc2, 0, 0, 0);
    acc2 = __builtin_amdgcn_mfma_f32_16x16x32_bf16(A[t][1], Bf[2][1], acc2, 0, 0, 0);
    acc3 = __builtin_amdgcn_mfma_f32_16x16x32_bf16(A[t][0], Bf[3][0], acc3, 0, 0, 0);
    acc3 = __builtin_amdgcn_mfma_f32_16x16x32_bf16(A[t][1], Bf[3][1], acc3, 0, 0, 0);
#pragma unroll
    for (int rg = 0; rg < 4; ++rg) {
      int row = q * 4 + rg;                  // C/D row = edge within tile
      int jd = __shfl(rec[t].y, row);        // dst-sorted msg row id (-1 = pad)
      if (jd >= 0) {
        unsigned p0 = (unsigned)f2bf(acc0[rg]) | ((unsigned)f2bf(acc1[rg]) << 16);
        unsigned p1 = (unsigned)f2bf(acc2[rg]) | ((unsigned)f2bf(acc3[rg]) << 16);
        u32x2 pk;
        pk.x = p0; pk.y = p1;
        *(u32x2*)(msgp + (long)jd * 32 + 2 * l15) = pk;   // one 8B store/lane
      }
    }
  }
}

// ---- Phase B fused: [optional weight compute] + aggregate + MFMA self-loop ----
// CW (layer 1): chunked pipeline per dst — stage relrow chunk in LDS, compute
// 1/cnt weights in LDS (also store wrow for L2), aggregate chunk via LDS weights.
// !CW (layer 2): stream weights from global wrow.
template <bool CW>
__global__ __launch_bounds__(256) void aggsl_kernel(
    const unsigned int* __restrict__ msgp, const int* __restrict__ dstoff,
    const int* __restrict__ relrow, float* __restrict__ wrow,
    const unsigned short* __restrict__ xbin, const unsigned short* __restrict__ WTl,
    float* __restrict__ outp, unsigned short* __restrict__ hb, int N) {
  __shared__ float aggs[64][66];             // +2 pad: 2-way max bank alias
  const int lane = (int)threadIdx.x & 63;
  const int wv = (int)threadIdx.x >> 6;
  const int base = blockIdx.x * 64;
  const int j = lane & 31;
  const int half = lane >> 5;
  // ---- phase 1: streaming weighted accumulate, 16 nodes per wave ----
  for (int i16 = 0; i16 < 16; ++i16) {
    const int d = base + wv * 16 + i16;
    if (d >= N) break;
    const int off = dstoff[d], end = dstoff[d + 1];
    const int deg = end - off;
    float f00 = 0.f, f01 = 0.f, f10 = 0.f, f11 = 0.f;
    float f20 = 0.f, f21 = 0.f, f30 = 0.f, f31 = 0.f;
    if constexpr (CW) {
      __shared__ int rsh[4][256];
      __shared__ int rsh2[4][256];
      float* wsh = (float*)rsh[wv];
      for (int c1 = 0; c1 < deg; c1 += 256) {
        const int n1 = min(256, deg - c1);
        for (int l = lane; l < n1; l += 64) rsh[wv][l] = relrow[off + c1 + l];
        __threadfence_block();
        int myrel[4], cnt[4];
#pragma unroll
        for (int k = 0; k < 4; ++k) {
          int l = k * 64 + lane;
          myrel[k] = (l < n1) ? rsh[wv][l] : -1;
          cnt[k] = 0;
        }
        for (int c2 = 0; c2 < deg; c2 += 256) {
          const int n2 = min(256, deg - c2);
          const int* rr2;
          if (c2 == c1) {
            rr2 = rsh[wv];
          } else {
            for (int l = lane; l < n2; l += 64) rsh2[wv][l] = relrow[off + c2 + l];
            __threadfence_block();
            rr2 = rsh2[wv];
          }
          for (int mm = 0; mm < n2; ++mm) {
            int rvv = rr2[mm];
#pragma unroll
            for (int k = 0; k < 4; ++k) cnt[k] += (rvv == myrel[k]) ? 1 : 0;
          }
        }
        __threadfence_block();               // wave-lockstep: reads done, overwrite ok
#pragma unroll
        for (int k = 0; k < 4; ++k) {
          int l = k * 64 + lane;
          if (l < n1) {
            float w = 1.0f / (float)cnt[k];
            wsh[l] = w;
            wrow[off + c1 + l] = w;          // persist for layer 2
          }
        }
        __threadfence_block();
        // aggregate this chunk using LDS weights
        const long gb = (long)off + c1;
        int i = half;
        for (; i + 6 < n1; i += 8) {
          float w0 = wsh[i], w1 = wsh[i + 2], w2 = wsh[i + 4], w3 = wsh[i + 6];
          unsigned u0 = msgp[(gb + i) * 32 + j];
          unsigned u1 = msgp[(gb + i + 2) * 32 + j];
          unsigned u2 = msgp[(gb + i + 4) * 32 + j];
          unsigned u3 = msgp[(gb + i + 6) * 32 + j];
          f00 = fmaf(w0, bflo(u0), f00); f01 = fmaf(w0, bfhi(u0), f01);
          f10 = fmaf(w1, bflo(u1), f10); f11 = fmaf(w1, bfhi(u1), f11);
          f20 = fmaf(w2, bflo(u2), f20); f21 = fmaf(w2, bfhi(u2), f21);
          f30 = fmaf(w3, bflo(u3), f30); f31 = fmaf(w3, bfhi(u3), f31);
        }
        for (; i + 2 < n1; i += 4) {
          float w0 = wsh[i], w1 = wsh[i + 2];
          unsigned u0 = msgp[(gb + i) * 32 + j];
          unsigned u1 = msgp[(gb + i + 2) * 32 + j];
          f00 = fmaf(w0, bflo(u0), f00); f01 = fmaf(w0, bfhi(u0), f01);
          f10 = fmaf(w1, bflo(u1), f10); f11 = fmaf(w1, bfhi(u1), f11);
        }
        if (i < n1) {
          float w0 = wsh[i];
          unsigned u0 = msgp[(gb + i) * 32 + j];
          f00 = fmaf(w0, bflo(u0), f00); f01 = fmaf(w0, bfhi(u0), f01);
        }
      }
    } else {
      int i = off + half;
      for (; i + 6 < end; i += 8) {          // 4 independent streams (MLP)
        float w0 = wrow[i];
        float w1 = wrow[i + 2];
        float w2 = wrow[i + 4];
        float w3 = wrow[i + 6];
        unsigned u0 = msgp[(long)i * 32 + j];
        unsigned u1 = msgp[(long)(i + 2) * 32 + j];
        unsigned u2 = msgp[(long)(i + 4) * 32 + j];
        unsigned u3 = msgp[(long)(i + 6) * 32 + j];
        f00 = fmaf(w0, bflo(u0), f00); f01 = fmaf(w0, bfhi(u0), f01);
        f10 = fmaf(w1, bflo(u1), f10); f11 = fmaf(w1, bfhi(u1), f11);
        f20 = fmaf(w2, bflo(u2), f20); f21 = fmaf(w2, bfhi(u2), f21);
        f30 = fmaf(w3, bflo(u3), f30); f31 = fmaf(w3, bfhi(u3), f31);
      }
      for (; i + 2 < end; i += 4) {
        float w0 = wrow[i];
        float w1 = wrow[i + 2];
        unsigned u0 = msgp[(long)i * 32 + j];
        unsigned u1 = msgp[(long)(i + 2) * 32 + j];
        f00 = fmaf(w0, bflo(u0), f00); f01 = fmaf(w0, bfhi(u0), f01);
        f10 = fmaf(w1, bflo(u1), f10); f11 = fmaf(w1, bfhi(u1), f11);
      }
      if (i < end) {
        float w0 = wrow[i];
        unsigned u0 = msgp[(long)i * 32 + j];
        f00 = fmaf(w0, bflo(u0), f00); f01 = fmaf(w0, bfhi(u0), f01);
      }
    }
    float aLo = (f00 + f10) + (f20 + f30), aHi = (f01 + f11) + (f21 + f31);
    aLo += __shfl_xor(aLo, 32);
    aHi += __shfl_xor(aHi, 32);
    if (half == 0) {
      const int k = j >> 1;
      const int colLo = (j & 1) ? 32 + k : k; // interleaved layout decode
      aggs[d - base][colLo] = aLo;
      aggs[d - base][colLo + 16] = aHi;
    }
  }
  __syncthreads();
  // ---- phase 2: MFMA self-loop for this wave's 16 rows ----
  const int l15 = lane & 15;
  const int q = lane >> 4;
  const int row0 = base + wv * 16;
  if (row0 >= N) return;
  bf16x8 Bf[4][2];
#pragma unroll
  for (int nt = 0; nt < 4; ++nt)
#pragma unroll
    for (int kh = 0; kh < 2; ++kh)
      Bf[nt][kh] = *(const bf16x8*)(WTl + (nt * 16 + l15) * 64 + kh * 32 + q * 8);
  const int m = min(row0 + l15, N - 1);
  const unsigned short* xr = xbin + ((long)m << 6);
  bf16x8 A0 = *(const bf16x8*)(xr + q * 8);
  bf16x8 A1 = *(const bf16x8*)(xr + 32 + q * 8);
  f32x4 acc[4];
#pragma unroll
  for (int nt = 0; nt < 4; ++nt)
#pragma unroll
    for (int rg = 0; rg < 4; ++rg) {
      int node = row0 + q * 4 + rg;
      acc[nt][rg] = (node < N) ? aggs[wv * 16 + q * 4 + rg][nt * 16 + l15] : 0.0f;
    }
#pragma unroll
  for (int nt = 0; nt < 4; ++nt) {
    acc[nt] = __builtin_amdgcn_mfma_f32_16x16x32_bf16(A0, Bf[nt][0], acc[nt], 0, 0, 0);
    acc[nt] = __builtin_amdgcn_mfma_f32_16x16x32_bf16(A1, Bf[nt][1], acc[nt], 0, 0, 0);
  }
#pragma unroll
  for (int rg = 0; rg < 4; ++rg) {
    int node = row0 + q * 4 + rg;
    if (node < N) {
#pragma unroll
      for (int nt = 0; nt < 4; ++nt) {
        float v = fmaxf(acc[nt][rg], 0.0f);
        if (outp) outp[(long)node * D + nt * 16 + l15] = v;
        if (hb) hb[(long)node * D + nt * 16 + l15] = f2bf(v);
      }
    }
  }
}

extern "C" void kernel_launch(void* const* d_in, const int* in_sizes, int n_in,
                              void* d_out, int out_size, void* d_ws, size_t ws_size,
                              hipStream_t stream) {
  const float* x   = (const float*)d_in[0];
  const int* src   = (const int*)d_in[1];
  const int* dst   = (const int*)d_in[2];
  const int* et    = (const int*)d_in[3];
  const float* W1  = (const float*)d_in[4];
  const float* Wl1 = (const float*)d_in[5];
  const float* W2  = (const float*)d_in[6];
  const float* Wl2 = (const float*)d_in[7];
  float* out = (float*)d_out;

  const int N = in_sizes[0] / D;
  const int E = in_sizes[1];
  const int R = in_sizes[4] / (D * D);

  const int Ecap = ((E + SEG - 1) & ~(SEG - 1)) + R * SEG;
  const int nwaves = Ecap / SEG;
  const int nbN = (N + 255) / 256;          // blocks over nodes (scan regions)
  const int nbE = (E + SBS - 1) / SBS;      // blocks over edges (count/scatter)
  const int nBC = R * nbE;                  // bcnt length
  const int nbBC = (nBC + 255) / 256;       // scan blocks over bcnt

  char* ws = (char*)d_ws;
  size_t off = 0;
  auto alloc = [&](size_t bytes) -> void* {
    void* p = (void*)(ws + off);
    off += (bytes + 255) & ~(size_t)255;
    return p;
  };
  int*   deg    = (int*)alloc((size_t)N * CSTR * sizeof(int));   // padded: 1/line
  int*   cur2   = (int*)alloc((size_t)N * CSTR * sizeof(int));   // padded: 1/line
  int*   bcnt   = (int*)alloc((size_t)nBC * sizeof(int));
  int*   prefE  = (int*)alloc((size_t)(nBC + 1) * sizeof(int));
  int*   bsum   = (int*)alloc((size_t)(nbBC + nbN) * sizeof(int));
  int*   dstoff = (int*)alloc((size_t)(N + 1) * sizeof(int));
  int*   relrow = (int*)alloc((size_t)E * sizeof(int));
  float* wrow   = (float*)alloc((size_t)E * sizeof(float));
  int*   wrel   = (int*)alloc((size_t)nwaves * sizeof(int));
  int2*  eidx   = (int2*)alloc((size_t)(Ecap + SEG) * sizeof(int2));
  unsigned int* msgp = (unsigned int*)alloc((size_t)E * 32 * sizeof(unsigned int));
  unsigned short* xb  = (unsigned short*)alloc((size_t)N * D * sizeof(unsigned short));
  unsigned short* hb  = (unsigned short*)alloc((size_t)N * D * sizeof(unsigned short));
  unsigned short* WT1 = (unsigned short*)alloc((size_t)R * D * D * sizeof(unsigned short));
  unsigned short* WT2 = (unsigned short*)alloc((size_t)R * D * D * sizeof(unsigned short));
  unsigned short* WTl1 = (unsigned short*)alloc((size_t)D * D * sizeof(unsigned short));
  unsigned short* WTl2 = (unsigned short*)alloc((size_t)D * D * sizeof(unsigned short));
  (void)ws_size; (void)n_in; (void)out_size;

  const int msg_blocks = (nwaves + 3) / 4;
  const int aggsl_blocks = (N + 63) / 64;
  const int nx = N * D;
  const int nxb = (nx + SBS * 8 - 1) / (SBS * 8); // xb convert blocks (8/thread)
  const int cc_blocks = nbE + nxb + 2 * R + 2;    // count + xb + W matrices

  // ---- shared preprocessing (only deg needs a memset) ----
  hipMemsetAsync(deg, 0, (size_t)N * CSTR * sizeof(int), stream);
  count_cvt_kernel<<<cc_blocks, SBS, 0, stream>>>(
      dst, et, bcnt, deg, E, R, nbE,
      x, xb, nx, nxb, W1, WT1, W2, WT2, Wl1, WTl1, Wl2, WTl2);
  scanA_dual_kernel<<<nbBC + nbN, 256, 0, stream>>>(bcnt, deg, bsum, nBC, N, nbBC);
  scanB_dual_kernel<<<1, 256, 0, stream>>>(bsum, nbBC, nbN);
  scanC_dual_kernel<<<nbBC + nbN, 256, 0, stream>>>(bcnt, deg, bsum, prefE,
                                                    dstoff, cur2, nBC, N, nbBC);
  scatter_kernel<<<nbE, SBS, 0, stream>>>(src, dst, et, prefE, cur2,
                                          eidx, wrel, E, R, nbE, Ecap, nwaves);

  // ---- layer 1 (msg writes relrow; aggsl computes + persists wrow) ----
  msg_kernel<<<msg_blocks, 256, 0, stream>>>(xb, WT1, eidx, wrel, msgp, relrow, nwaves);
  aggsl_kernel<true><<<aggsl_blocks, 256, 0, stream>>>(
      msgp, dstoff, relrow, wrow, xb, WTl1, nullptr, hb, N);

  // ---- layer 2 (wrow already valid) ----
  msg_kernel<<<msg_blocks, 256, 0, stream>>>(hb, WT2, eidx, wrel, msgp, nullptr, nwaves);
  aggsl_kernel<false><<<aggsl_blocks, 256, 0, stream>>>(
      msgp, dstoff, nullptr, wrow, hb, WTl2, out, nullptr, N);
}

// Round 10
// 313.848 us; speedup vs baseline: 1.0496x; 1.0496x over previous
//
#include <hip/hip_runtime.h>

typedef __attribute__((ext_vector_type(8))) short bf16x8;
typedef __attribute__((ext_vector_type(4))) float f32x4;
typedef __attribute__((ext_vector_type(2))) unsigned int u32x2;

constexpr int D = 64;
constexpr int SEG = 64;    // relation-segment padding granule = edges per wave
constexpr int CSTR = 16;   // counter stride (ints): 1 atomic counter per 64B line
constexpr int SBS = 1024;  // scatter/count block size (edges per block)

__device__ inline unsigned short f2bf(float f) {  // RNE fp32->bf16
  unsigned u = __float_as_uint(f);
  u += 0x7fff + ((u >> 16) & 1);
  return (unsigned short)(u >> 16);
}
__device__ inline float bflo(unsigned u) { return __uint_as_float(u << 16); }
__device__ inline float bfhi(unsigned u) { return __uint_as_float(u & 0xffff0000u); }

// ---- counting (blocks < nbE) + fused convert (blocks >= nbE) ----
__global__ __launch_bounds__(SBS) void count_cvt_kernel(
    const int* __restrict__ dst, const int* __restrict__ et,
    int* __restrict__ bcnt, int* __restrict__ deg, int E, int R, int nbE,
    const float* __restrict__ x, unsigned short* __restrict__ xb, int nx, int nxb,
    const float* __restrict__ W1, unsigned short* __restrict__ WT1,
    const float* __restrict__ W2, unsigned short* __restrict__ WT2,
    const float* __restrict__ Wl1, unsigned short* __restrict__ WTl1,
    const float* __restrict__ Wl2, unsigned short* __restrict__ WTl2) {
  int b = blockIdx.x;
  int t = threadIdx.x;
  if (b < nbE) {
    __shared__ int lh[128];
    if (t < 128) lh[t] = 0;
    __syncthreads();
    int e = b * SBS + t;
    if (e < E) {
      atomicAdd(&deg[(long)dst[e] * CSTR], 1);   // one counter per cache line
      atomicAdd(&lh[et[e]], 1);
    }
    __syncthreads();
    if (t < R) bcnt[t * nbE + b] = lh[t];
    return;
  }
  b -= nbE;
  if (b < nxb) {
    long i = ((long)b * SBS + t) * 8;
    if (i < nx) {                            // nx % 8 == 0 (N*D, D=64)
      float4 f0 = *(const float4*)(x + i);
      float4 f1 = *(const float4*)(x + i + 4);
      bf16x8 o;
      o[0] = (short)f2bf(f0.x); o[1] = (short)f2bf(f0.y);
      o[2] = (short)f2bf(f0.z); o[3] = (short)f2bf(f0.w);
      o[4] = (short)f2bf(f1.x); o[5] = (short)f2bf(f1.y);
      o[6] = (short)f2bf(f1.z); o[7] = (short)f2bf(f1.w);
      *(bf16x8*)(xb + i) = o;
    }
    return;
  }
  const int m = b - nxb;                     // matrix index in [0, 2R+2)
  const float* Wsrc;
  unsigned short* Wdst;
  if (m < R)          { Wsrc = W1 + ((long)m << 12);        Wdst = WT1 + ((long)m << 12); }
  else if (m < 2 * R) { Wsrc = W2 + ((long)(m - R) << 12);  Wdst = WT2 + ((long)(m - R) << 12); }
  else if (m == 2 * R){ Wsrc = Wl1;                         Wdst = WTl1; }
  else                { Wsrc = Wl2;                         Wdst = WTl2; }
  __shared__ float tile[64][65];
#pragma unroll
  for (int it = 0; it < 4; ++it) {
    int idx = it * SBS + t;                  // k = idx>>6 (row), n = idx&63 (col)
    tile[idx >> 6][idx & 63] = Wsrc[idx];
  }
  __syncthreads();
#pragma unroll
  for (int it = 0; it < 4; ++it) {
    int j = it * SBS + t;                    // out index: n = j>>6, k = j&63
    Wdst[j] = f2bf(tile[j & 63][j >> 6]);    // coalesced bf16 store
  }
}

// ---- dual-region 3-phase exclusive scan: bcnt (dense) + deg (strided) ----
__global__ __launch_bounds__(256) void scanA_dual_kernel(
    const int* __restrict__ bcnt, const int* __restrict__ deg,
    int* __restrict__ bsum, int nBC, int N, int nbBC) {
  __shared__ int s[256];
  int t = threadIdx.x;
  int b = blockIdx.x;
  int v;
  if (b < nbBC) {
    int i = b * 256 + t;
    v = (i < nBC) ? bcnt[i] : 0;
  } else {
    int i = (b - nbBC) * 256 + t;
    v = (i < N) ? deg[(long)i * CSTR] : 0;
  }
  s[t] = v;
  __syncthreads();
  for (int o = 128; o > 0; o >>= 1) {
    if (t < o) s[t] += s[t + o];
    __syncthreads();
  }
  if (t == 0) bsum[b] = s[0];
}

__device__ inline void scanB_region(int* bsum, int nb, int t) {
  __shared__ int s[256];
  __shared__ int carry;
  if (t == 0) carry = 0;
  __syncthreads();
  for (int base = 0; base < nb; base += 256) {
    int i = base + t;
    int v = (i < nb) ? bsum[i] : 0;
    s[t] = v;
    __syncthreads();
    for (int o = 1; o < 256; o <<= 1) {
      int u = (t >= o) ? s[t - o] : 0;
      __syncthreads();
      s[t] += u;
      __syncthreads();
    }
    if (i < nb) bsum[i] = carry + s[t] - v;   // exclusive
    __syncthreads();
    if (t == 0) carry += s[255];
    __syncthreads();
  }
}

__global__ __launch_bounds__(256) void scanB_dual_kernel(
    int* __restrict__ bsum, int nbBC, int nbN) {
  int t = threadIdx.x;
  scanB_region(bsum, nbBC, t);
  scanB_region(bsum + nbBC, nbN, t);
}

// blocks < nbBC: bcnt -> prefE (+ total); blocks >= nbBC: deg -> dstoff/cur2
__global__ __launch_bounds__(256) void scanC_dual_kernel(
    const int* __restrict__ bcnt, const int* __restrict__ deg,
    const int* __restrict__ bsum, int* __restrict__ prefE,
    int* __restrict__ dstoff, int* __restrict__ cur2,
    int nBC, int N, int nbBC) {
  __shared__ int s[256];
  int t = threadIdx.x;
  int b = blockIdx.x;
  bool isBC = (b < nbBC);
  int i = (isBC ? b : b - nbBC) * 256 + t;
  int n = isBC ? nBC : N;
  int v = 0;
  if (i < n) v = isBC ? bcnt[i] : deg[(long)i * CSTR];
  s[t] = v;
  __syncthreads();
  for (int o = 1; o < 256; o <<= 1) {
    int u = (t >= o) ? s[t - o] : 0;
    __syncthreads();
    s[t] += u;
    __syncthreads();
  }
  int excl = bsum[b] + s[t] - v;
  if (isBC) {
    if (i < n) prefE[i] = excl;
    if (i == n - 1) prefE[n] = excl + v;
  } else {
    if (i < n) { dstoff[i] = excl; cur2[(long)i * CSTR] = excl; }
    if (i == n - 1) dstoff[n] = excl + v;
  }
}

// ---- counting-sort scatter with inline padded-cursor scan + pad fills ----
__global__ __launch_bounds__(SBS) void scatter_kernel(
    const int* __restrict__ src, const int* __restrict__ dst, const int* __restrict__ et,
    const int* __restrict__ prefE, int* __restrict__ cur2,
    int2* __restrict__ eidx, int* __restrict__ wrel,
    int E, int R, int nbE, int Ecap, int nwavesTot) {
  __shared__ int lh[128];
  __shared__ int lbase[128];
  __shared__ int lpre[128];
  __shared__ int scur[128];
  __shared__ int stot[128];
  __shared__ int sv[SBS];
  __shared__ int jv[SBS];
  __shared__ int rv[SBS];
  int t = threadIdx.x, b = blockIdx.x;
  // ---- inline padded cursor scan over relations ----
  int myc = 0, mytot = 0;
  if (t < 128) {
    if (t < R) {
      mytot = prefE[(t + 1) * nbE] - prefE[t * nbE];
      myc = (mytot + SEG - 1) & ~(SEG - 1);
    }
    lpre[t] = myc;
  }
  __syncthreads();
  for (int o = 1; o < 128; o <<= 1) {
    int u = (t >= o && t < 128) ? lpre[t - o] : 0;
    __syncthreads();
    if (t < 128) lpre[t] += u;
    __syncthreads();
  }
  if (t < 128) {
    scur[t] = lpre[t] - myc;                 // exclusive padded prefix = cursor
    stot[t] = mytot;
    lh[t] = 0;
    lbase[t] = (t < R) ? (scur[t] + prefE[t * nbE + b] - prefE[t * nbE]) : 0;
  }
  __syncthreads();
  // ---- distributed pad fills (relations grid-strided over blocks) ----
  for (int rr = b; rr <= R; rr += nbE) {
    if (rr < R) {
      int cur = scur[rr], tot = stot[rr];
      int c = (tot + SEG - 1) & ~(SEG - 1);
      for (int p = cur + tot + t; p < cur + c; p += SBS) eidx[p] = make_int2(-1, -1);
      int w0 = cur >> 6, nw2 = c >> 6;
      for (int w = t; w < nw2; w += SBS) wrel[w0 + w] = rr;
    } else {
      int total = scur[127];                 // padded grand total (c=0 for t>=R)
      for (int p = total + t; p < Ecap; p += SBS) eidx[p] = make_int2(-1, -1);
      for (int w = (total >> 6) + t; w < nwavesTot; w += SBS) wrel[w] = 0;
    }
  }
  // ---- main scatter ----
  int e = b * SBS + t;
  bool valid = (e < E);
  int r = 0, s = 0, jd = 0, lr = 0;
  if (valid) {
    r = et[e]; s = src[e]; int d = dst[e];
    lr = atomicAdd(&lh[r], 1);                    // within-block rank (LDS)
    jd = atomicAdd(&cur2[(long)d * CSTR], 1);     // own line -> pipelined RMW
  }
  __syncthreads();
  if (t < 128) lpre[t] = lh[t];
  __syncthreads();
  for (int o = 1; o < 128; o <<= 1) {             // inclusive scan of lh
    int u = (t >= o && t < 128) ? lpre[t - o] : 0;
    __syncthreads();
    if (t < 128) lpre[t] += u;
    __syncthreads();
  }
  if (valid) {
    int slot = (lpre[r] - lh[r]) + lr;            // exclusive base + rank
    sv[slot] = s; jv[slot] = jd; rv[slot] = r;
  }
  __syncthreads();
  int nvalid = min(E - b * SBS, SBS);
  if (t < nvalid) {
    int rr2 = rv[t];
    int ex = lpre[rr2] - lh[rr2];
    int pos = lbase[rr2] + (t - ex);              // consecutive t -> consecutive pos
    eidx[pos] = make_int2(sv[t], jv[t]);
  }
}

// ---- Phase A: MFMA matvec, stream raw msgs; deep-pipelined loads ----
// msg row layout (32 dwords, interleaved): dword 2k = cols (k, k+16);
// dword 2k+1 = cols (32+k, 48+k). One uint2 (8B) store per lane per edge-row.
__global__ __launch_bounds__(256)
void msg_kernel(const unsigned short* __restrict__ xb,
                const unsigned short* __restrict__ WT,
                const int2* __restrict__ eidx, const int* __restrict__ wrel,
                unsigned int* __restrict__ msgp, int* __restrict__ relrow, int nwaves) {
  const int lane = (int)threadIdx.x & 63;
  const int l15 = lane & 15;
  const int q = lane >> 4;
  // bijective XCD swizzle (T1): contiguous wave (=relation) ranges per XCD
  const int nwg = (int)gridDim.x;
  const int bid = (int)blockIdx.x;
  const int xcd = bid & 7, idx = bid >> 3;
  const int qq = nwg >> 3, rr = nwg & 7;
  const int swz = (xcd < rr ? xcd * (qq + 1) : rr * (qq + 1) + (xcd - rr) * qq) + idx;
  const int wave = swz * 4 + ((int)threadIdx.x >> 6);
  if (wave >= nwaves) return;
  const long base = (long)wave * SEG;
  const int r = wrel[wave];                 // wave-uniform relation (0 for pad tail)
  const unsigned short* wb = WT + ((long)r << 12);
  int2 rec[4];
#pragma unroll
  for (int t = 0; t < 4; ++t) rec[t] = eidx[base + t * 16 + l15];
  bf16x8 Bf[4][2];
#pragma unroll
  for (int nt = 0; nt < 4; ++nt)
#pragma unroll
    for (int kh = 0; kh < 2; ++kh)
      Bf[nt][kh] = *(const bf16x8*)(wb + (nt * 16 + l15) * 64 + kh * 32 + q * 8);
  bf16x8 A[4][2];
#pragma unroll
  for (int t = 0; t < 4; ++t) {
    const unsigned short* xr = xb + ((long)max(rec[t].x, 0) << 6);
    A[t][0] = *(const bf16x8*)(xr + q * 8);
    A[t][1] = *(const bf16x8*)(xr + 32 + q * 8);
  }
  if (relrow) {                              // graph-invariant: L1 only
#pragma unroll
    for (int t = 0; t < 4; ++t)
      if (lane < 16 && rec[t].y >= 0) relrow[rec[t].y] = r;
  }
#pragma unroll
  for (int t = 0; t < 4; ++t) {
    f32x4 acc0 = (f32x4)0.0f, acc1 = (f32x4)0.0f, acc2 = (f32x4)0.0f, acc3 = (f32x4)0.0f;
    acc0 = __builtin_amdgcn_mfma_f32_16x16x32_bf16(A[t][0], Bf[0][0], acc0, 0, 0, 0);
    acc0 = __builtin_amdgcn_mfma_f32_16x16x32_bf16(A[t][1], Bf[0][1], acc0, 0, 0, 0);
    acc1 = __builtin_amdgcn_mfma_f32_16x16x32_bf16(A[t][0], Bf[1][0], acc1, 0, 0, 0);
    acc1 = __builtin_amdgcn_mfma_f32_16x16x32_bf16(A[t][1], Bf[1][1], acc1, 0, 0, 0);
    acc2 = __builtin_amdgcn_mfma_f32_16x16x32_bf16(A[t][0], Bf[2][0], acc2, 0, 0, 0);
    acc2 = __builtin_amdgcn_mfma_f32_16x16x32_bf16(A[t][1], Bf[2][1], acc2, 0, 0, 0);
    acc3 = __builtin_amdgcn_mfma_f32_16x16x32_bf16(A[t][0], Bf[3][0], acc3, 0, 0, 0);
    acc3 = __builtin_amdgcn_mfma_f32_16x16x32_bf16(A[t][1], Bf[3][1], acc3, 0, 0, 0);
#pragma unroll
    for (int rg = 0; rg < 4; ++rg) {
      int row = q * 4 + rg;                  // C/D row = edge within tile
      int jd = __shfl(rec[t].y, row);        // dst-sorted msg row id (-1 = pad)
      if (jd >= 0) {
        unsigned p0 = (unsigned)f2bf(acc0[rg]) | ((unsigned)f2bf(acc1[rg]) << 16);
        unsigned p1 = (unsigned)f2bf(acc2[rg]) | ((unsigned)f2bf(acc3[rg]) << 16);
        u32x2 pk;
        pk.x = p0; pk.y = p1;
        *(u32x2*)(msgp + (long)jd * 32 + 2 * l15) = pk;   // one 8B store/lane
      }
    }
  }
}

// ---- weight precompute (once per graph): wrow[jd] = 1/cnt(dst,rel) ----
__global__ __launch_bounds__(256) void weight_kernel(
    const int* __restrict__ relrow, const int* __restrict__ dstoff,
    float* __restrict__ wrow, int N) {
  __shared__ int rsh[4][256];
  const int wv = (int)threadIdx.x >> 6;
  const int lane = (int)threadIdx.x & 63;
  const int d = blockIdx.x * 4 + wv;
  if (d >= N) return;
  const int off = dstoff[d], end = dstoff[d + 1];
  const int deg = end - off;
  if (deg <= 0) return;
  if (deg <= 256) {
    const int nit = (deg + 63) >> 6;
    for (int it = 0; it < nit; ++it) {
      int l = it * 64 + lane;
      if (l < deg) rsh[wv][l] = relrow[off + l];
    }
    __threadfence_block();
    for (int it = 0; it < nit; ++it) {
      int l = it * 64 + lane;
      if (l < deg) {
        int rv = rsh[wv][l];
        int c = 0;
        for (int m = 0; m < deg; ++m) c += (rsh[wv][m] == rv) ? 1 : 0;
        wrow[off + l] = 1.0f / (float)c;
      }
    }
  } else {
    for (int l = lane; l < deg; l += 64) {
      int rv = relrow[off + l];
      int c = 0;
      for (int m = off; m < end; ++m) c += (relrow[m] == rv) ? 1 : 0;
      wrow[off + l] = 1.0f / (float)c;
    }
  }
}

// ---- Phase B fused: aggregate 64-node tile into LDS, then MFMA self-loop ----
__global__ __launch_bounds__(256) void aggsl_kernel(
    const unsigned int* __restrict__ msgp, const int* __restrict__ dstoff,
    const float* __restrict__ wrow,
    const unsigned short* __restrict__ xbin, const unsigned short* __restrict__ WTl,
    float* __restrict__ outp, unsigned short* __restrict__ hb, int N) {
  __shared__ float aggs[64][66];             // +2 pad: 2-way max bank alias
  const int lane = (int)threadIdx.x & 63;
  const int wv = (int)threadIdx.x >> 6;
  const int base = blockIdx.x * 64;
  const int j = lane & 31;
  const int half = lane >> 5;
  // ---- phase 1: streaming weighted accumulate, 16 nodes per wave ----
  for (int i16 = 0; i16 < 16; ++i16) {
    const int d = base + wv * 16 + i16;
    if (d >= N) break;
    const int off = dstoff[d], end = dstoff[d + 1];
    float f00 = 0.f, f01 = 0.f, f10 = 0.f, f11 = 0.f;
    float f20 = 0.f, f21 = 0.f, f30 = 0.f, f31 = 0.f;
    int i = off + half;
    for (; i + 6 < end; i += 8) {            // 4 independent streams (MLP)
      float w0 = wrow[i];
      float w1 = wrow[i + 2];
      float w2 = wrow[i + 4];
      float w3 = wrow[i + 6];
      unsigned u0 = msgp[(long)i * 32 + j];
      unsigned u1 = msgp[(long)(i + 2) * 32 + j];
      unsigned u2 = msgp[(long)(i + 4) * 32 + j];
      unsigned u3 = msgp[(long)(i + 6) * 32 + j];
      f00 = fmaf(w0, bflo(u0), f00); f01 = fmaf(w0, bfhi(u0), f01);
      f10 = fmaf(w1, bflo(u1), f10); f11 = fmaf(w1, bfhi(u1), f11);
      f20 = fmaf(w2, bflo(u2), f20); f21 = fmaf(w2, bfhi(u2), f21);
      f30 = fmaf(w3, bflo(u3), f30); f31 = fmaf(w3, bfhi(u3), f31);
    }
    for (; i + 2 < end; i += 4) {
      float w0 = wrow[i];
      float w1 = wrow[i + 2];
      unsigned u0 = msgp[(long)i * 32 + j];
      unsigned u1 = msgp[(long)(i + 2) * 32 + j];
      f00 = fmaf(w0, bflo(u0), f00); f01 = fmaf(w0, bfhi(u0), f01);
      f10 = fmaf(w1, bflo(u1), f10); f11 = fmaf(w1, bfhi(u1), f11);
    }
    if (i < end) {
      float w0 = wrow[i];
      unsigned u0 = msgp[(long)i * 32 + j];
      f00 = fmaf(w0, bflo(u0), f00); f01 = fmaf(w0, bfhi(u0), f01);
    }
    float aLo = (f00 + f10) + (f20 + f30), aHi = (f01 + f11) + (f21 + f31);
    aLo += __shfl_xor(aLo, 32);
    aHi += __shfl_xor(aHi, 32);
    if (half == 0) {
      const int k = j >> 1;
      const int colLo = (j & 1) ? 32 + k : k; // interleaved layout decode
      aggs[d - base][colLo] = aLo;
      aggs[d - base][colLo + 16] = aHi;
    }
  }
  __syncthreads();
  // ---- phase 2: MFMA self-loop for this wave's 16 rows ----
  const int l15 = lane & 15;
  const int q = lane >> 4;
  const int row0 = base + wv * 16;
  if (row0 >= N) return;
  bf16x8 Bf[4][2];
#pragma unroll
  for (int nt = 0; nt < 4; ++nt)
#pragma unroll
    for (int kh = 0; kh < 2; ++kh)
      Bf[nt][kh] = *(const bf16x8*)(WTl + (nt * 16 + l15) * 64 + kh * 32 + q * 8);
  const int m = min(row0 + l15, N - 1);
  const unsigned short* xr = xbin + ((long)m << 6);
  bf16x8 A0 = *(const bf16x8*)(xr + q * 8);
  bf16x8 A1 = *(const bf16x8*)(xr + 32 + q * 8);
  f32x4 acc[4];
#pragma unroll
  for (int nt = 0; nt < 4; ++nt)
#pragma unroll
    for (int rg = 0; rg < 4; ++rg) {
      int node = row0 + q * 4 + rg;
      acc[nt][rg] = (node < N) ? aggs[wv * 16 + q * 4 + rg][nt * 16 + l15] : 0.0f;
    }
#pragma unroll
  for (int nt = 0; nt < 4; ++nt) {
    acc[nt] = __builtin_amdgcn_mfma_f32_16x16x32_bf16(A0, Bf[nt][0], acc[nt], 0, 0, 0);
    acc[nt] = __builtin_amdgcn_mfma_f32_16x16x32_bf16(A1, Bf[nt][1], acc[nt], 0, 0, 0);
  }
#pragma unroll
  for (int rg = 0; rg < 4; ++rg) {
    int node = row0 + q * 4 + rg;
    if (node < N) {
#pragma unroll
      for (int nt = 0; nt < 4; ++nt) {
        float v = fmaxf(acc[nt][rg], 0.0f);
        if (outp) outp[(long)node * D + nt * 16 + l15] = v;
        if (hb) hb[(long)node * D + nt * 16 + l15] = f2bf(v);
      }
    }
  }
}

extern "C" void kernel_launch(void* const* d_in, const int* in_sizes, int n_in,
                              void* d_out, int out_size, void* d_ws, size_t ws_size,
                              hipStream_t stream) {
  const float* x   = (const float*)d_in[0];
  const int* src   = (const int*)d_in[1];
  const int* dst   = (const int*)d_in[2];
  const int* et    = (const int*)d_in[3];
  const float* W1  = (const float*)d_in[4];
  const float* Wl1 = (const float*)d_in[5];
  const float* W2  = (const float*)d_in[6];
  const float* Wl2 = (const float*)d_in[7];
  float* out = (float*)d_out;

  const int N = in_sizes[0] / D;
  const int E = in_sizes[1];
  const int R = in_sizes[4] / (D * D);

  const int Ecap = ((E + SEG - 1) & ~(SEG - 1)) + R * SEG;
  const int nwaves = Ecap / SEG;
  const int nbN = (N + 255) / 256;          // blocks over nodes (scan regions)
  const int nbE = (E + SBS - 1) / SBS;      // blocks over edges (count/scatter)
  const int nBC = R * nbE;                  // bcnt length
  const int nbBC = (nBC + 255) / 256;       // scan blocks over bcnt

  char* ws = (char*)d_ws;
  size_t off = 0;
  auto alloc = [&](size_t bytes) -> void* {
    void* p = (void*)(ws + off);
    off += (bytes + 255) & ~(size_t)255;
    return p;
  };
  int*   deg    = (int*)alloc((size_t)N * CSTR * sizeof(int));   // padded: 1/line
  int*   cur2   = (int*)alloc((size_t)N * CSTR * sizeof(int));   // padded: 1/line
  int*   bcnt   = (int*)alloc((size_t)nBC * sizeof(int));
  int*   prefE  = (int*)alloc((size_t)(nBC + 1) * sizeof(int));
  int*   bsum   = (int*)alloc((size_t)(nbBC + nbN) * sizeof(int));
  int*   dstoff = (int*)alloc((size_t)(N + 1) * sizeof(int));
  int*   relrow = (int*)alloc((size_t)E * sizeof(int));
  float* wrow   = (float*)alloc((size_t)E * sizeof(float));
  int*   wrel   = (int*)alloc((size_t)nwaves * sizeof(int));
  int2*  eidx   = (int2*)alloc((size_t)(Ecap + SEG) * sizeof(int2));
  unsigned int* msgp = (unsigned int*)alloc((size_t)E * 32 * sizeof(unsigned int));
  unsigned short* xb  = (unsigned short*)alloc((size_t)N * D * sizeof(unsigned short));
  unsigned short* hb  = (unsigned short*)alloc((size_t)N * D * sizeof(unsigned short));
  unsigned short* WT1 = (unsigned short*)alloc((size_t)R * D * D * sizeof(unsigned short));
  unsigned short* WT2 = (unsigned short*)alloc((size_t)R * D * D * sizeof(unsigned short));
  unsigned short* WTl1 = (unsigned short*)alloc((size_t)D * D * sizeof(unsigned short));
  unsigned short* WTl2 = (unsigned short*)alloc((size_t)D * D * sizeof(unsigned short));
  (void)ws_size; (void)n_in; (void)out_size;

  const int msg_blocks = (nwaves + 3) / 4;
  const int w_blocks = (N + 3) / 4;
  const int aggsl_blocks = (N + 63) / 64;
  const int nx = N * D;
  const int nxb = (nx + SBS * 8 - 1) / (SBS * 8); // xb convert blocks (8/thread)
  const int cc_blocks = nbE + nxb + 2 * R + 2;    // count + xb + W matrices

  // ---- shared preprocessing (only deg needs a memset) ----
  hipMemsetAsync(deg, 0, (size_t)N * CSTR * sizeof(int), stream);
  count_cvt_kernel<<<cc_blocks, SBS, 0, stream>>>(
      dst, et, bcnt, deg, E, R, nbE,
      x, xb, nx, nxb, W1, WT1, W2, WT2, Wl1, WTl1, Wl2, WTl2);
  scanA_dual_kernel<<<nbBC + nbN, 256, 0, stream>>>(bcnt, deg, bsum, nBC, N, nbBC);
  scanB_dual_kernel<<<1, 256, 0, stream>>>(bsum, nbBC, nbN);
  scanC_dual_kernel<<<nbBC + nbN, 256, 0, stream>>>(bcnt, deg, bsum, prefE,
                                                    dstoff, cur2, nBC, N, nbBC);
  scatter_kernel<<<nbE, SBS, 0, stream>>>(src, dst, et, prefE, cur2,
                                          eidx, wrel, E, R, nbE, Ecap, nwaves);

  // ---- layer 1 (msg writes relrow; weight precompute once) ----
  msg_kernel<<<msg_blocks, 256, 0, stream>>>(xb, WT1, eidx, wrel, msgp, relrow, nwaves);
  weight_kernel<<<w_blocks, 256, 0, stream>>>(relrow, dstoff, wrow, N);
  aggsl_kernel<<<aggsl_blocks, 256, 0, stream>>>(msgp, dstoff, wrow, xb, WTl1,
                                                 nullptr, hb, N);

  // ---- layer 2 (wrow already valid) ----
  msg_kernel<<<msg_blocks, 256, 0, stream>>>(hb, WT2, eidx, wrel, msgp, nullptr, nwaves);
  aggsl_kernel<<<aggsl_blocks, 256, 0, stream>>>(msgp, dstoff, wrow, hb, WTl2,
                                                 out, nullptr, N);
}